// Round 8
// baseline (369.650 us; speedup 1.0000x reference)
//
#include <hip/hip_runtime.h>
#include <hip/hip_bf16.h>

typedef unsigned short u16;
typedef unsigned int   u32;

__device__ __forceinline__ float bf2f(u32 bits) { return __uint_as_float(bits << 16); }
__device__ __forceinline__ u32 f2bf_bits(float x) {           // RNE, finite inputs
    u32 u = __float_as_uint(x);
    return (u + 0x7fffu + ((u >> 16) & 1u)) >> 16;
}

// ---------------- dtype detection ----------------
// fp32 buffers: low 16 bits are random mantissa -> ~1/256 words look like bf16
// exponent 0xFF. Real bf16 normals never do. (R3 measured: harness feeds fp32.)
__global__ __launch_bounds__(256) void detect_f32(const u32* __restrict__ w, int nwords, int* __restrict__ flag)
{
    __shared__ int s_hit;
    int t = threadIdx.x;
    if (t == 0) s_hit = 0;
    __syncthreads();
    int hit = 0;
    for (int i = t; i < nwords; i += 256) {
        u32 lo = w[i] & 0xffffu;
        if (((lo >> 7) & 0xffu) == 0xffu) hit = 1;
    }
    if (hit) atomicOr(&s_hit, 1);
    __syncthreads();
    if (t == 0) *flag = s_hit;     // 1 = fp32 inputs, 0 = bf16 inputs
}

// ---------------- param conversion (-> fp32 into ws) ----------------
// P layout (floats): W0[8192] W1[4096] W2[4096] al0[64] ar0[64] b0[64]
//                    al1[64] ar1[64] b1[64] al2[64] ar2[64] b2[64]  = 16960
__global__ __launch_bounds__(256) void cvt_params(
    const int* __restrict__ flag,
    const void* __restrict__ W0, const void* __restrict__ al0, const void* __restrict__ ar0, const void* __restrict__ b0,
    const void* __restrict__ W1, const void* __restrict__ al1, const void* __restrict__ ar1, const void* __restrict__ b1,
    const void* __restrict__ W2, const void* __restrict__ al2, const void* __restrict__ ar2, const void* __restrict__ b2,
    float* __restrict__ P)
{
    int i = blockIdx.x * 256 + threadIdx.x;
    const void* s; int off;
    if      (i < 8192)  { s = W0;  off = 0;     }
    else if (i < 12288) { s = W1;  off = 8192;  }
    else if (i < 16384) { s = W2;  off = 12288; }
    else if (i < 16448) { s = al0; off = 16384; }
    else if (i < 16512) { s = ar0; off = 16448; }
    else if (i < 16576) { s = b0;  off = 16512; }
    else if (i < 16640) { s = al1; off = 16576; }
    else if (i < 16704) { s = ar1; off = 16640; }
    else if (i < 16768) { s = b1;  off = 16704; }
    else if (i < 16832) { s = al2; off = 16768; }
    else if (i < 16896) { s = ar2; off = 16832; }
    else if (i < 16960) { s = b2;  off = 16896; }
    else return;
    int j = i - off;
    P[i] = (*flag) ? ((const float*)s)[j] : bf2f(((const u16*)s)[j]);
}

// ---------------- CSR build (dst shared by all 3 layers) ----------------
__global__ __launch_bounds__(256) void zero_int(int* __restrict__ p, int n)
{
    int i = blockIdx.x * 256 + threadIdx.x;
    if (i < n) p[i] = 0;
}

// hist + per-edge rank (removes atomics from the scatter pass)
__global__ __launch_bounds__(256) void hist_rank(
    const int* __restrict__ dst, int* __restrict__ deg, int* __restrict__ rank, int E)
{
    int e = blockIdx.x * 256 + threadIdx.x;
    if (e < E) rank[e] = atomicAdd(&deg[dst[e]], 1);
}

// single-kernel exclusive scan over NP ints (NP multiple of 1024).
__global__ __launch_bounds__(1024) void scan_all(
    const int* __restrict__ deg, int* __restrict__ row_start, int NP4)
{
    __shared__ int sm[1024];
    int t = threadIdx.x;
    int per = (NP4 + 1023) >> 10;
    int lo = t * per; if (lo > NP4) lo = NP4;
    int hi = lo + per; if (hi > NP4) hi = NP4;
    const int4* d4 = (const int4*)deg;
    int sum = 0;
    for (int j = lo; j < hi; j++) { int4 v = d4[j]; sum += v.x + v.y + v.z + v.w; }
    sm[t] = sum;
    __syncthreads();
#pragma unroll
    for (int off = 1; off < 1024; off <<= 1) {
        int a = (t >= off) ? sm[t - off] : 0;
        __syncthreads();
        sm[t] += a;
        __syncthreads();
    }
    int run = sm[t] - sum;                 // exclusive prefix of this chunk
    int4* r4 = (int4*)row_start;
    for (int j = lo; j < hi; j++) {
        int4 v = d4[j];
        int4 r;
        r.x = run;
        r.y = run + v.x;
        r.z = r.y + v.y;
        r.w = r.z + v.z;
        r4[j] = r;
        run = r.w + v.w;
    }
}

// atomic-free scatter using precomputed ranks
__global__ __launch_bounds__(256) void scatter_kernel(
    const int* __restrict__ src, const int* __restrict__ dst, const int* __restrict__ rank,
    const int* __restrict__ row_start, int* __restrict__ csr_src, int E)
{
    int e = blockIdx.x * 256 + threadIdx.x;
    if (e < E) csr_src[row_start[dst[e]] + rank[e]] = src[e];
}

// ---------------- GEMM + attention dots: 64 rows x 4 col-group waves ----------------
template<int F_IN, int H, bool LAYER0>
__global__ __launch_bounds__(256) void gemm_attn(
    const int* __restrict__ flag, const void* __restrict__ xv,
    const float* __restrict__ Wf, const float* __restrict__ alf, const float* __restrict__ arf,
    u16* __restrict__ fo, float* __restrict__ el, float* __restrict__ er, int N)
{
    int lane = threadIdx.x & 63;
    int cg   = __builtin_amdgcn_readfirstlane(threadIdx.x >> 6);   // 0..3
    int n    = blockIdx.x * 64 + lane;
    bool act = (n < N);

    float acc[16];
#pragma unroll
    for (int c = 0; c < 16; c++) acc[c] = 0.f;

    const float* Wcol = Wf + cg * 16;
    bool f32in = LAYER0 ? (*flag != 0) : false;

    if (act) {
        if (f32in) {
            const float* x = (const float*)xv + (size_t)n * F_IN;
            for (int k0 = 0; k0 < F_IN; k0 += 4) {
                float4 u = *reinterpret_cast<const float4*>(x + k0);
                float xs[4] = {u.x, u.y, u.z, u.w};
#pragma unroll
                for (int j = 0; j < 4; j++) {
                    const float* w = Wcol + (size_t)(k0 + j) * 64;   // scalar loads
#pragma unroll
                    for (int c = 0; c < 16; c++) acc[c] = fmaf(xs[j], w[c], acc[c]);
                }
            }
        } else {
            const u16* x = (const u16*)xv + (size_t)n * F_IN;
            for (int k0 = 0; k0 < F_IN; k0 += 8) {
                uint4 u = *reinterpret_cast<const uint4*>(x + k0);
                float xs[8];
                xs[0] = bf2f(u.x & 0xffffu); xs[1] = bf2f(u.x >> 16);
                xs[2] = bf2f(u.y & 0xffffu); xs[3] = bf2f(u.y >> 16);
                xs[4] = bf2f(u.z & 0xffffu); xs[5] = bf2f(u.z >> 16);
                xs[6] = bf2f(u.w & 0xffffu); xs[7] = bf2f(u.w >> 16);
#pragma unroll
                for (int j = 0; j < 8; j++) {
                    const float* w = Wcol + (size_t)(k0 + j) * 64;
#pragma unroll
                    for (int c = 0; c < 16; c++) acc[c] = fmaf(xs[j], w[c], acc[c]);
                }
            }
        }
    }

    float e1 = 0.f, e2 = 0.f;
#pragma unroll
    for (int c = 0; c < 16; c++) {
        e1 = fmaf(acc[c], alf[cg * 16 + c], e1);
        e2 = fmaf(acc[c], arf[cg * 16 + c], e2);
    }
    if constexpr (H == 4) {
        if (act) {
            el[(size_t)n * 4 + cg] = e1;
            er[(size_t)n * 4 + cg] = e2;
        }
    } else {             // H == 1: reduce partial dots across the 4 waves
        __shared__ float sel_[4][64];
        __shared__ float ser_[4][64];
        sel_[cg][lane] = e1;
        ser_[cg][lane] = e2;
        __syncthreads();
        if (cg == 0 && act) {
            el[n] = sel_[0][lane] + sel_[1][lane] + sel_[2][lane] + sel_[3][lane];
            er[n] = ser_[0][lane] + ser_[1][lane] + ser_[2][lane] + ser_[3][lane];
        }
    }

    if (act) {
        u16* dp = fo + (size_t)n * 64 + cg * 16;
        uint4 v;
        v.x = f2bf_bits(acc[0])  | (f2bf_bits(acc[1])  << 16);
        v.y = f2bf_bits(acc[2])  | (f2bf_bits(acc[3])  << 16);
        v.z = f2bf_bits(acc[4])  | (f2bf_bits(acc[5])  << 16);
        v.w = f2bf_bits(acc[6])  | (f2bf_bits(acc[7])  << 16);
        *reinterpret_cast<uint4*>(dp) = v;
        v.x = f2bf_bits(acc[8])  | (f2bf_bits(acc[9])  << 16);
        v.y = f2bf_bits(acc[10]) | (f2bf_bits(acc[11]) << 16);
        v.z = f2bf_bits(acc[12]) | (f2bf_bits(acc[13]) << 16);
        v.w = f2bf_bits(acc[14]) | (f2bf_bits(acc[15]) << 16);
        *reinterpret_cast<uint4*>(dp + 8) = v;
    }
}

// ---------------- wave-per-node softmax aggregation (uniform scalar indices) ----------------
// n is readfirstlane-uniform -> row_start/csr_src/el/er loads take the scalar
// (s_load) path; only the 128B fo row gather stays on the vector pipe.
// Scores |v| <~ 15 << 88 (fp32 exp overflow): plain exp is safe.
__device__ __forceinline__ float sel4(float4 v, int h) {
    float r = (h == 0) ? v.x : (h == 1) ? v.y : (h == 2) ? v.z : v.w;
    return r;
}

template<int H, bool FINAL>
__global__ __launch_bounds__(256) void aggregate(
    const int* __restrict__ flag,
    const u16* __restrict__ fo, const float* __restrict__ el, const float* __restrict__ er,
    const int* __restrict__ row_start, const int* __restrict__ csr_src,
    const float* __restrict__ bias, void* __restrict__ outp, int N)
{
    int lane = threadIdx.x & 63;
    int n = __builtin_amdgcn_readfirstlane((blockIdx.x * 256 + threadIdx.x) >> 6);
    if (n >= N) return;
    int h = lane >> 4;                      // head for H=4 (16 lanes each)
    float erh;
    if constexpr (H == 4) erh = sel4(((const float4*)er)[n], h);   // uniform s_load
    else                  erh = er[n];
    int i0 = row_start[n], i1 = row_start[n + 1];
    float s0 = 0.f, s1 = 0.f, a0 = 0.f, a1 = 0.f;
    int i = i0;

    auto score = [&](int s) -> float {
        float v;
        if constexpr (H == 4) v = sel4(((const float4*)el)[s], h) + erh;
        else                  v = el[s] + erh;
        v = fmaxf(v, 0.2f * v);             // leaky_relu(0.2)
        return __expf(v);
    };

    // 8-wide batches: 8 scalar index loads -> 8 independent fo gathers in flight
    for (; i + 8 <= i1; i += 8) {
        int sA = csr_src[i+0], sB = csr_src[i+1], sC = csr_src[i+2], sD = csr_src[i+3];
        int sE = csr_src[i+4], sF = csr_src[i+5], sG = csr_src[i+6], sH = csr_src[i+7];
        float fA = bf2f(fo[(size_t)sA * 64 + lane]);
        float fB = bf2f(fo[(size_t)sB * 64 + lane]);
        float fC = bf2f(fo[(size_t)sC * 64 + lane]);
        float fD = bf2f(fo[(size_t)sD * 64 + lane]);
        float fE = bf2f(fo[(size_t)sE * 64 + lane]);
        float fF = bf2f(fo[(size_t)sF * 64 + lane]);
        float fG = bf2f(fo[(size_t)sG * 64 + lane]);
        float fH = bf2f(fo[(size_t)sH * 64 + lane]);
        float eA = score(sA), eB = score(sB), eC = score(sC), eD = score(sD);
        float eE = score(sE), eF = score(sF), eG = score(sG), eH = score(sH);
        s0 += (eA + eC) + (eE + eG);
        s1 += (eB + eD) + (eF + eH);
        a0 = fmaf(eA, fA, a0); a1 = fmaf(eB, fB, a1);
        a0 = fmaf(eC, fC, a0); a1 = fmaf(eD, fD, a1);
        a0 = fmaf(eE, fE, a0); a1 = fmaf(eF, fF, a1);
        a0 = fmaf(eG, fG, a0); a1 = fmaf(eH, fH, a1);
    }
    // 4-wide batch
    for (; i + 4 <= i1; i += 4) {
        int sA = csr_src[i+0], sB = csr_src[i+1], sC = csr_src[i+2], sD = csr_src[i+3];
        float fA = bf2f(fo[(size_t)sA * 64 + lane]);
        float fB = bf2f(fo[(size_t)sB * 64 + lane]);
        float fC = bf2f(fo[(size_t)sC * 64 + lane]);
        float fD = bf2f(fo[(size_t)sD * 64 + lane]);
        float eA = score(sA), eB = score(sB), eC = score(sC), eD = score(sD);
        s0 += eA + eC;  s1 += eB + eD;
        a0 = fmaf(eA, fA, a0); a1 = fmaf(eB, fB, a1);
        a0 = fmaf(eC, fC, a0); a1 = fmaf(eD, fD, a1);
    }
    // remainder
    for (; i < i1; i++) {
        int s = csr_src[i];
        float fv = bf2f(fo[(size_t)s * 64 + lane]);
        float ex = score(s);
        s0 += ex;
        a0 = fmaf(ex, fv, a0);
    }

    float sumex = s0 + s1;
    float acc   = a0 + a1;
    float o = (i1 > i0) ? (acc / sumex + bias[lane]) : bias[lane];   // 0-in-degree -> bias
    size_t idx = (size_t)n * 64 + lane;
    if constexpr (!FINAL) {
        o = o > 0.f ? o : expm1f(o);                   // ELU
        ((u16*)outp)[idx] = f2bf_bits(o);
    } else {
        if (*flag) ((float*)outp)[idx] = o;
        else       ((u16*)outp)[idx]   = f2bf_bits(o);
    }
}

extern "C" void kernel_launch(void* const* d_in, const int* in_sizes, int n_in,
                              void* d_out, int out_size, void* d_ws, size_t ws_size,
                              hipStream_t stream)
{
    const void* h   = d_in[0];
    const int*  src = (const int*)d_in[1];
    const int*  dst = (const int*)d_in[2];

    const int N  = in_sizes[0] / 128;
    const int E  = in_sizes[1];
    const int NP = (N + 1023) & ~1023;     // padded for int4 scan

    // ---- workspace carve-out (~22 MB) ----
    char* ws = (char*)d_ws;
    size_t off = 0;
    auto take = [&](size_t bytes) -> char* {
        char* p = ws + off;
        off = (off + bytes + 255) & ~(size_t)255;
        return p;
    };
    float* P         = (float*)take(16960 * 4);
    int*   flag      = (int*)  take(256);
    float* el        = (float*)take((size_t)N * 4 * 4);
    float* er        = (float*)take((size_t)N * 4 * 4);
    int*   deg       = (int*)  take((size_t)NP * 4);
    int*   row_start = (int*)  take((size_t)NP * 4);   // covers N+1
    int*   rank      = (int*)  take((size_t)E * 4);
    int*   csr_src   = (int*)  take((size_t)E * 4);
    u16*   f         = (u16*)  take((size_t)N * 64 * 2);   // bf16 activations
    u16*   x1        = (u16*)  take((size_t)N * 64 * 2);
    if (off > ws_size) x1 = (u16*)d_out;   // fallback: x1 in d_out (consumed before final write)

    float* Wf0  = P;          float* Wf1  = P + 8192;  float* Wf2  = P + 12288;
    float* alf0 = P + 16384;  float* arf0 = P + 16448; float* bf0  = P + 16512;
    float* alf1 = P + 16576;  float* arf1 = P + 16640; float* bf1  = P + 16704;
    float* alf2 = P + 16768;  float* arf2 = P + 16832; float* bf2  = P + 16896;

    detect_f32<<<1, 256, 0, stream>>>((const u32*)h, 8192, flag);
    cvt_params<<<67, 256, 0, stream>>>(flag,
        d_in[3], d_in[4], d_in[5], d_in[6],
        d_in[7], d_in[8], d_in[9], d_in[10],
        d_in[11], d_in[12], d_in[13], d_in[14], P);
    zero_int<<<(NP + 255) / 256, 256, 0, stream>>>(deg, NP);
    hist_rank<<<(E + 255) / 256, 256, 0, stream>>>(dst, deg, rank, E);
    scan_all<<<1, 1024, 0, stream>>>(deg, row_start, NP / 4);
    scatter_kernel<<<(E + 255) / 256, 256, 0, stream>>>(src, dst, rank, row_start, csr_src, E);

    int gemm_blocks = (N + 63) / 64;          // 4 waves/block, 16 cols each
    int agg_blocks  = (N * 64 + 255) / 256;   // one 64-lane wave per node

    // layer 0: 128 -> 4x16
    gemm_attn<128, 4, true ><<<gemm_blocks, 256, 0, stream>>>(flag, h,  Wf0, alf0, arf0, f, el, er, N);
    aggregate<4, false><<<agg_blocks, 256, 0, stream>>>(flag, f, el, er, row_start, csr_src, bf0, x1, N);
    // layer 1: 64 -> 4x16
    gemm_attn<64, 4, false><<<gemm_blocks, 256, 0, stream>>>(flag, x1, Wf1, alf1, arf1, f, el, er, N);
    aggregate<4, false><<<agg_blocks, 256, 0, stream>>>(flag, f, el, er, row_start, csr_src, bf1, x1, N);
    // layer 2: 64 -> 1x64 (final)
    gemm_attn<64, 1, false><<<gemm_blocks, 256, 0, stream>>>(flag, x1, Wf2, alf2, arf2, f, el, er, N);
    aggregate<1, true ><<<agg_blocks, 256, 0, stream>>>(flag, f, el, er, row_start, csr_src, bf2, d_out, N);
}

// Round 9
// 367.796 us; speedup vs baseline: 1.0050x; 1.0050x over previous
//
#include <hip/hip_runtime.h>
#include <hip/hip_bf16.h>

typedef unsigned short u16;
typedef unsigned int   u32;

__device__ __forceinline__ float bf2f(u32 bits) { return __uint_as_float(bits << 16); }
__device__ __forceinline__ u32 f2bf_bits(float x) {           // RNE, finite inputs
    u32 u = __float_as_uint(x);
    return (u + 0x7fffu + ((u >> 16) & 1u)) >> 16;
}

// ---------------- fused setup: dtype detect + param cvt + deg zero ----------------
// Blocks [0,67): detect fp32-vs-bf16 over 8192 words of h (fp32 low halves are
// random mantissa -> ~1/256 have bf16 exponent 0xFF; miss prob ~e^-32), then
// convert params into P. Blocks [67,...): zero deg[NP].
// P layout (floats): W0[8192] W1[4096] W2[4096] al0[64] ar0[64] b0[64]
//                    al1[64] ar1[64] b1[64] al2[64] ar2[64] b2[64]  = 16960
__global__ __launch_bounds__(256) void setup_kernel(
    const u32* __restrict__ hw, int* __restrict__ flag, int* __restrict__ deg, int NP,
    const void* __restrict__ W0, const void* __restrict__ al0, const void* __restrict__ ar0, const void* __restrict__ b0,
    const void* __restrict__ W1, const void* __restrict__ al1, const void* __restrict__ ar1, const void* __restrict__ b1,
    const void* __restrict__ W2, const void* __restrict__ al2, const void* __restrict__ ar2, const void* __restrict__ b2,
    float* __restrict__ P)
{
    if (blockIdx.x >= 67) {
        int i = (blockIdx.x - 67) * 256 + threadIdx.x;
        if (i < NP) deg[i] = 0;
        return;
    }
    __shared__ int s_hit;
    if (threadIdx.x == 0) s_hit = 0;
    __syncthreads();
    int hit = 0;
    for (int i = threadIdx.x; i < 8192; i += 256) {
        u32 lo = hw[i] & 0xffffu;
        if (((lo >> 7) & 0xffu) == 0xffu) hit = 1;
    }
    if (hit) atomicOr(&s_hit, 1);
    __syncthreads();
    int f32 = s_hit;
    if (blockIdx.x == 0 && threadIdx.x == 0) *flag = f32;   // 1 = fp32 inputs

    int i = blockIdx.x * 256 + threadIdx.x;
    const void* s; int off;
    if      (i < 8192)  { s = W0;  off = 0;     }
    else if (i < 12288) { s = W1;  off = 8192;  }
    else if (i < 16384) { s = W2;  off = 12288; }
    else if (i < 16448) { s = al0; off = 16384; }
    else if (i < 16512) { s = ar0; off = 16448; }
    else if (i < 16576) { s = b0;  off = 16512; }
    else if (i < 16640) { s = al1; off = 16576; }
    else if (i < 16704) { s = ar1; off = 16640; }
    else if (i < 16768) { s = b1;  off = 16704; }
    else if (i < 16832) { s = al2; off = 16768; }
    else if (i < 16896) { s = ar2; off = 16832; }
    else if (i < 16960) { s = b2;  off = 16896; }
    else return;
    int j = i - off;
    P[i] = f32 ? ((const float*)s)[j] : bf2f(((const u16*)s)[j]);
}

// hist + per-edge rank (removes atomics from the scatter pass)
__global__ __launch_bounds__(256) void hist_rank(
    const int* __restrict__ dst, int* __restrict__ deg, int* __restrict__ rank, int E)
{
    int e = blockIdx.x * 256 + threadIdx.x;
    if (e < E) rank[e] = atomicAdd(&deg[dst[e]], 1);
}

// single-kernel exclusive scan over NP ints (NP multiple of 1024).
__global__ __launch_bounds__(1024) void scan_all(
    const int* __restrict__ deg, int* __restrict__ row_start, int NP4)
{
    __shared__ int sm[1024];
    int t = threadIdx.x;
    int per = (NP4 + 1023) >> 10;
    int lo = t * per; if (lo > NP4) lo = NP4;
    int hi = lo + per; if (hi > NP4) hi = NP4;
    const int4* d4 = (const int4*)deg;
    int sum = 0;
    for (int j = lo; j < hi; j++) { int4 v = d4[j]; sum += v.x + v.y + v.z + v.w; }
    sm[t] = sum;
    __syncthreads();
#pragma unroll
    for (int off = 1; off < 1024; off <<= 1) {
        int a = (t >= off) ? sm[t - off] : 0;
        __syncthreads();
        sm[t] += a;
        __syncthreads();
    }
    int run = sm[t] - sum;                 // exclusive prefix of this chunk
    int4* r4 = (int4*)row_start;
    for (int j = lo; j < hi; j++) {
        int4 v = d4[j];
        int4 r;
        r.x = run;
        r.y = run + v.x;
        r.z = r.y + v.y;
        r.w = r.z + v.z;
        r4[j] = r;
        run = r.w + v.w;
    }
}

// atomic-free scatter using precomputed ranks
__global__ __launch_bounds__(256) void scatter_kernel(
    const int* __restrict__ src, const int* __restrict__ dst, const int* __restrict__ rank,
    const int* __restrict__ row_start, int* __restrict__ csr_src, int E)
{
    int e = blockIdx.x * 256 + threadIdx.x;
    if (e < E) csr_src[row_start[dst[e]] + rank[e]] = src[e];
}

// ---------------- GEMM + attention dots: 64 rows x 4 col-group waves ----------------
template<int F_IN, int H, bool LAYER0>
__global__ __launch_bounds__(256) void gemm_attn(
    const int* __restrict__ flag, const void* __restrict__ xv,
    const float* __restrict__ Wf, const float* __restrict__ alf, const float* __restrict__ arf,
    u16* __restrict__ fo, float* __restrict__ el, float* __restrict__ er, int N)
{
    int lane = threadIdx.x & 63;
    int cg   = __builtin_amdgcn_readfirstlane(threadIdx.x >> 6);   // 0..3
    int n    = blockIdx.x * 64 + lane;
    bool act = (n < N);

    float acc[16];
#pragma unroll
    for (int c = 0; c < 16; c++) acc[c] = 0.f;

    const float* Wcol = Wf + cg * 16;
    bool f32in = LAYER0 ? (*flag != 0) : false;

    if (act) {
        if (f32in) {
            const float* x = (const float*)xv + (size_t)n * F_IN;
            for (int k0 = 0; k0 < F_IN; k0 += 4) {
                float4 u = *reinterpret_cast<const float4*>(x + k0);
                float xs[4] = {u.x, u.y, u.z, u.w};
#pragma unroll
                for (int j = 0; j < 4; j++) {
                    const float* w = Wcol + (size_t)(k0 + j) * 64;   // scalar loads
#pragma unroll
                    for (int c = 0; c < 16; c++) acc[c] = fmaf(xs[j], w[c], acc[c]);
                }
            }
        } else {
            const u16* x = (const u16*)xv + (size_t)n * F_IN;
            for (int k0 = 0; k0 < F_IN; k0 += 8) {
                uint4 u = *reinterpret_cast<const uint4*>(x + k0);
                float xs[8];
                xs[0] = bf2f(u.x & 0xffffu); xs[1] = bf2f(u.x >> 16);
                xs[2] = bf2f(u.y & 0xffffu); xs[3] = bf2f(u.y >> 16);
                xs[4] = bf2f(u.z & 0xffffu); xs[5] = bf2f(u.z >> 16);
                xs[6] = bf2f(u.w & 0xffffu); xs[7] = bf2f(u.w >> 16);
#pragma unroll
                for (int j = 0; j < 8; j++) {
                    const float* w = Wcol + (size_t)(k0 + j) * 64;
#pragma unroll
                    for (int c = 0; c < 16; c++) acc[c] = fmaf(xs[j], w[c], acc[c]);
                }
            }
        }
    }

    float e1 = 0.f, e2 = 0.f;
#pragma unroll
    for (int c = 0; c < 16; c++) {
        e1 = fmaf(acc[c], alf[cg * 16 + c], e1);
        e2 = fmaf(acc[c], arf[cg * 16 + c], e2);
    }
    if constexpr (H == 4) {
        if (act) {
            el[(size_t)n * 4 + cg] = e1;
            er[(size_t)n * 4 + cg] = e2;
        }
    } else {             // H == 1: reduce partial dots across the 4 waves
        __shared__ float sel_[4][64];
        __shared__ float ser_[4][64];
        sel_[cg][lane] = e1;
        ser_[cg][lane] = e2;
        __syncthreads();
        if (cg == 0 && act) {
            el[n] = sel_[0][lane] + sel_[1][lane] + sel_[2][lane] + sel_[3][lane];
            er[n] = ser_[0][lane] + ser_[1][lane] + ser_[2][lane] + ser_[3][lane];
        }
    }

    if (act) {
        u16* dp = fo + (size_t)n * 64 + cg * 16;
        uint4 v;
        v.x = f2bf_bits(acc[0])  | (f2bf_bits(acc[1])  << 16);
        v.y = f2bf_bits(acc[2])  | (f2bf_bits(acc[3])  << 16);
        v.z = f2bf_bits(acc[4])  | (f2bf_bits(acc[5])  << 16);
        v.w = f2bf_bits(acc[6])  | (f2bf_bits(acc[7])  << 16);
        *reinterpret_cast<uint4*>(dp) = v;
        v.x = f2bf_bits(acc[8])  | (f2bf_bits(acc[9])  << 16);
        v.y = f2bf_bits(acc[10]) | (f2bf_bits(acc[11]) << 16);
        v.z = f2bf_bits(acc[12]) | (f2bf_bits(acc[13]) << 16);
        v.w = f2bf_bits(acc[14]) | (f2bf_bits(acc[15]) << 16);
        *reinterpret_cast<uint4*>(dp + 8) = v;
    }
}

// ---------------- softmax aggregation: 2 waves per node, LDS combine ----------------
// R5's proven inner loop (lane-replicated vector loads — NOT scalar-pipe, per R8),
// but each node's edges are split even/odd across two waves: per-wave dependent
// chain halves, wave count doubles (better latency hiding at same total work).
// No max-subtraction: |scores| <~ 15 << 88 (fp32 exp overflow) -> sums associative.
template<int H, bool FINAL>
__global__ __launch_bounds__(256) void aggregate(
    const int* __restrict__ flag,
    const u16* __restrict__ fo, const float* __restrict__ el, const float* __restrict__ er,
    const int* __restrict__ row_start, const int* __restrict__ csr_src,
    const float* __restrict__ bias, void* __restrict__ outp, int N)
{
    __shared__ float s_acc[2][2][64];
    __shared__ float s_sum[2][2][64];
    int tid  = threadIdx.x;
    int lane = tid & 63;
    int wv   = (tid >> 6) & 1;               // which half of the node's edges
    int slot = tid >> 7;                     // node slot within block (0/1)
    int n    = blockIdx.x * 2 + slot;
    if (n >= N) n = N - 1;                   // duplicate work, identical writes (benign)
    constexpr int D = 64 / H;
    int h = lane / D;
    float erh = er[(size_t)n * H + h];
    int i0 = row_start[n], i1 = row_start[n + 1];
    float s0 = 0.f, s1 = 0.f, a0 = 0.f, a1 = 0.f;
    int i = i0 + wv;                         // this wave: i0+wv, i0+wv+2, ...
    for (; i + 6 < i1; i += 8) {             // 4 edges/batch (stride 2)
        int sA = csr_src[i], sB = csr_src[i + 2], sC = csr_src[i + 4], sD = csr_src[i + 6];
        float vA = el[(size_t)sA * H + h] + erh;
        float vB = el[(size_t)sB * H + h] + erh;
        float vC = el[(size_t)sC * H + h] + erh;
        float vD = el[(size_t)sD * H + h] + erh;
        float fA = bf2f(fo[(size_t)sA * 64 + lane]);
        float fB = bf2f(fo[(size_t)sB * 64 + lane]);
        float fC = bf2f(fo[(size_t)sC * 64 + lane]);
        float fD = bf2f(fo[(size_t)sD * 64 + lane]);
        vA = fmaxf(vA, 0.2f * vA); vB = fmaxf(vB, 0.2f * vB);
        vC = fmaxf(vC, 0.2f * vC); vD = fmaxf(vD, 0.2f * vD);
        float eA = __expf(vA), eB = __expf(vB), eC = __expf(vC), eD = __expf(vD);
        s0 += eA + eC;  s1 += eB + eD;
        a0 = fmaf(eA, fA, a0); a1 = fmaf(eB, fB, a1);
        a0 = fmaf(eC, fC, a0); a1 = fmaf(eD, fD, a1);
    }
    for (; i < i1; i += 2) {
        int s = csr_src[i];
        float v = el[(size_t)s * H + h] + erh;
        v = fmaxf(v, 0.2f * v);
        float ex = __expf(v);
        float fv = bf2f(fo[(size_t)s * 64 + lane]);
        s0 += ex;
        a0 = fmaf(ex, fv, a0);
    }
    s_acc[slot][wv][lane] = a0 + a1;
    s_sum[slot][wv][lane] = s0 + s1;
    __syncthreads();
    if (wv) return;
    float acc   = s_acc[slot][0][lane] + s_acc[slot][1][lane];
    float sumex = s_sum[slot][0][lane] + s_sum[slot][1][lane];
    float o = (i1 > i0) ? (acc / sumex + bias[lane]) : bias[lane];   // 0-in-degree -> bias
    size_t idx = (size_t)n * 64 + lane;
    if constexpr (!FINAL) {
        o = o > 0.f ? o : expm1f(o);                   // ELU
        ((u16*)outp)[idx] = f2bf_bits(o);
    } else {
        if (*flag) ((float*)outp)[idx] = o;
        else       ((u16*)outp)[idx]   = f2bf_bits(o);
    }
}

extern "C" void kernel_launch(void* const* d_in, const int* in_sizes, int n_in,
                              void* d_out, int out_size, void* d_ws, size_t ws_size,
                              hipStream_t stream)
{
    const void* h   = d_in[0];
    const int*  src = (const int*)d_in[1];
    const int*  dst = (const int*)d_in[2];

    const int N  = in_sizes[0] / 128;
    const int E  = in_sizes[1];
    const int NP = (N + 1023) & ~1023;     // padded for int4 scan

    // ---- workspace carve-out (~22 MB) ----
    char* ws = (char*)d_ws;
    size_t off = 0;
    auto take = [&](size_t bytes) -> char* {
        char* p = ws + off;
        off = (off + bytes + 255) & ~(size_t)255;
        return p;
    };
    float* P         = (float*)take(16960 * 4);
    int*   flag      = (int*)  take(256);
    float* el        = (float*)take((size_t)N * 4 * 4);
    float* er        = (float*)take((size_t)N * 4 * 4);
    int*   deg       = (int*)  take((size_t)NP * 4);
    int*   row_start = (int*)  take((size_t)NP * 4);   // covers N+1
    int*   rank      = (int*)  take((size_t)E * 4);
    int*   csr_src   = (int*)  take((size_t)E * 4);
    u16*   f         = (u16*)  take((size_t)N * 64 * 2);   // bf16 activations
    u16*   x1        = (u16*)  take((size_t)N * 64 * 2);
    if (off > ws_size) x1 = (u16*)d_out;   // fallback: x1 in d_out (consumed before final write)

    float* Wf0  = P;          float* Wf1  = P + 8192;  float* Wf2  = P + 12288;
    float* alf0 = P + 16384;  float* arf0 = P + 16448; float* bf0  = P + 16512;
    float* alf1 = P + 16576;  float* arf1 = P + 16640; float* bf1  = P + 16704;
    float* alf2 = P + 16768;  float* arf2 = P + 16832; float* bf2  = P + 16896;

    int setup_blocks = 67 + (NP + 255) / 256;
    setup_kernel<<<setup_blocks, 256, 0, stream>>>((const u32*)h, flag, deg, NP,
        d_in[3], d_in[4], d_in[5], d_in[6],
        d_in[7], d_in[8], d_in[9], d_in[10],
        d_in[11], d_in[12], d_in[13], d_in[14], P);
    hist_rank<<<(E + 255) / 256, 256, 0, stream>>>(dst, deg, rank, E);
    scan_all<<<1, 1024, 0, stream>>>(deg, row_start, NP / 4);
    scatter_kernel<<<(E + 255) / 256, 256, 0, stream>>>(src, dst, rank, row_start, csr_src, E);

    int gemm_blocks = (N + 63) / 64;          // 4 waves/block, 16 cols each
    int agg_blocks  = (N + 1) / 2;            // 2 nodes/block, 2 waves/node

    // layer 0: 128 -> 4x16
    gemm_attn<128, 4, true ><<<gemm_blocks, 256, 0, stream>>>(flag, h,  Wf0, alf0, arf0, f, el, er, N);
    aggregate<4, false><<<agg_blocks, 256, 0, stream>>>(flag, f, el, er, row_start, csr_src, bf0, x1, N);
    // layer 1: 64 -> 4x16
    gemm_attn<64, 4, false><<<gemm_blocks, 256, 0, stream>>>(flag, x1, Wf1, alf1, arf1, f, el, er, N);
    aggregate<4, false><<<agg_blocks, 256, 0, stream>>>(flag, f, el, er, row_start, csr_src, bf1, x1, N);
    // layer 2: 64 -> 1x64 (final)
    gemm_attn<64, 1, false><<<gemm_blocks, 256, 0, stream>>>(flag, x1, Wf2, alf2, arf2, f, el, er, N);
    aggregate<1, true ><<<agg_blocks, 256, 0, stream>>>(flag, f, el, er, row_start, csr_src, bf2, d_out, N);
}

// Round 10
// 324.367 us; speedup vs baseline: 1.1396x; 1.1339x over previous
//
#include <hip/hip_runtime.h>
#include <hip/hip_bf16.h>

typedef unsigned short u16;
typedef unsigned int   u32;

__device__ __forceinline__ float bf2f(u32 bits) { return __uint_as_float(bits << 16); }
__device__ __forceinline__ u32 f2bf_bits(float x) {           // RNE, finite inputs
    u32 u = __float_as_uint(x);
    return (u + 0x7fffu + ((u >> 16) & 1u)) >> 16;
}

// ---------------- fused setup: dtype detect + param cvt + deg zero ----------------
// Blocks [0,67): detect fp32-vs-bf16 over 8192 words of h (fp32 low halves are
// random mantissa -> ~1/256 have bf16 exponent 0xFF; miss prob ~e^-32), then
// convert params into P. Blocks [67,...): zero deg[NP].
// P layout (floats): W0[8192] W1[4096] W2[4096] al0[64] ar0[64] b0[64]
//                    al1[64] ar1[64] b1[64] al2[64] ar2[64] b2[64]  = 16960
__global__ __launch_bounds__(256) void setup_kernel(
    const u32* __restrict__ hw, int* __restrict__ flag, int* __restrict__ deg, int NP,
    const void* __restrict__ W0, const void* __restrict__ al0, const void* __restrict__ ar0, const void* __restrict__ b0,
    const void* __restrict__ W1, const void* __restrict__ al1, const void* __restrict__ ar1, const void* __restrict__ b1,
    const void* __restrict__ W2, const void* __restrict__ al2, const void* __restrict__ ar2, const void* __restrict__ b2,
    float* __restrict__ P)
{
    if (blockIdx.x >= 67) {
        int i = (blockIdx.x - 67) * 256 + threadIdx.x;
        if (i < NP) deg[i] = 0;
        return;
    }
    __shared__ int s_hit;
    if (threadIdx.x == 0) s_hit = 0;
    __syncthreads();
    int hit = 0;
    for (int i = threadIdx.x; i < 8192; i += 256) {
        u32 lo = hw[i] & 0xffffu;
        if (((lo >> 7) & 0xffu) == 0xffu) hit = 1;
    }
    if (hit) atomicOr(&s_hit, 1);
    __syncthreads();
    int f32 = s_hit;
    if (blockIdx.x == 0 && threadIdx.x == 0) *flag = f32;   // 1 = fp32 inputs

    int i = blockIdx.x * 256 + threadIdx.x;
    const void* s; int off;
    if      (i < 8192)  { s = W0;  off = 0;     }
    else if (i < 12288) { s = W1;  off = 8192;  }
    else if (i < 16384) { s = W2;  off = 12288; }
    else if (i < 16448) { s = al0; off = 16384; }
    else if (i < 16512) { s = ar0; off = 16448; }
    else if (i < 16576) { s = b0;  off = 16512; }
    else if (i < 16640) { s = al1; off = 16576; }
    else if (i < 16704) { s = ar1; off = 16640; }
    else if (i < 16768) { s = b1;  off = 16704; }
    else if (i < 16832) { s = al2; off = 16768; }
    else if (i < 16896) { s = ar2; off = 16832; }
    else if (i < 16960) { s = b2;  off = 16896; }
    else return;
    int j = i - off;
    P[i] = f32 ? ((const float*)s)[j] : bf2f(((const u16*)s)[j]);
}

// hist + per-edge rank (removes atomics from the scatter pass)
__global__ __launch_bounds__(256) void hist_rank(
    const int* __restrict__ dst, int* __restrict__ deg, int* __restrict__ rank, int E)
{
    int e = blockIdx.x * 256 + threadIdx.x;
    if (e < E) rank[e] = atomicAdd(&deg[dst[e]], 1);
}

// single-kernel exclusive scan over NP ints (NP multiple of 1024).
__global__ __launch_bounds__(1024) void scan_all(
    const int* __restrict__ deg, int* __restrict__ row_start, int NP4)
{
    __shared__ int sm[1024];
    int t = threadIdx.x;
    int per = (NP4 + 1023) >> 10;
    int lo = t * per; if (lo > NP4) lo = NP4;
    int hi = lo + per; if (hi > NP4) hi = NP4;
    const int4* d4 = (const int4*)deg;
    int sum = 0;
    for (int j = lo; j < hi; j++) { int4 v = d4[j]; sum += v.x + v.y + v.z + v.w; }
    sm[t] = sum;
    __syncthreads();
#pragma unroll
    for (int off = 1; off < 1024; off <<= 1) {
        int a = (t >= off) ? sm[t - off] : 0;
        __syncthreads();
        sm[t] += a;
        __syncthreads();
    }
    int run = sm[t] - sum;                 // exclusive prefix of this chunk
    int4* r4 = (int4*)row_start;
    for (int j = lo; j < hi; j++) {
        int4 v = d4[j];
        int4 r;
        r.x = run;
        r.y = run + v.x;
        r.z = r.y + v.y;
        r.w = r.z + v.z;
        r4[j] = r;
        run = r.w + v.w;
    }
}

// atomic-free scatter using precomputed ranks
__global__ __launch_bounds__(256) void scatter_kernel(
    const int* __restrict__ src, const int* __restrict__ dst, const int* __restrict__ rank,
    const int* __restrict__ row_start, int* __restrict__ csr_src, int E)
{
    int e = blockIdx.x * 256 + threadIdx.x;
    if (e < E) csr_src[row_start[dst[e]] + rank[e]] = src[e];
}

// ---------------- GEMM + attention dots: 64 rows x 4 col-group waves ----------------
template<int F_IN, int H, bool LAYER0>
__global__ __launch_bounds__(256) void gemm_attn(
    const int* __restrict__ flag, const void* __restrict__ xv,
    const float* __restrict__ Wf, const float* __restrict__ alf, const float* __restrict__ arf,
    u16* __restrict__ fo, float* __restrict__ el, float* __restrict__ er, int N)
{
    int lane = threadIdx.x & 63;
    int cg   = __builtin_amdgcn_readfirstlane(threadIdx.x >> 6);   // 0..3
    int n    = blockIdx.x * 64 + lane;
    bool act = (n < N);

    float acc[16];
#pragma unroll
    for (int c = 0; c < 16; c++) acc[c] = 0.f;

    const float* Wcol = Wf + cg * 16;
    bool f32in = LAYER0 ? (*flag != 0) : false;

    if (act) {
        if (f32in) {
            const float* x = (const float*)xv + (size_t)n * F_IN;
            for (int k0 = 0; k0 < F_IN; k0 += 4) {
                float4 u = *reinterpret_cast<const float4*>(x + k0);
                float xs[4] = {u.x, u.y, u.z, u.w};
#pragma unroll
                for (int j = 0; j < 4; j++) {
                    const float* w = Wcol + (size_t)(k0 + j) * 64;   // scalar loads
#pragma unroll
                    for (int c = 0; c < 16; c++) acc[c] = fmaf(xs[j], w[c], acc[c]);
                }
            }
        } else {
            const u16* x = (const u16*)xv + (size_t)n * F_IN;
            for (int k0 = 0; k0 < F_IN; k0 += 8) {
                uint4 u = *reinterpret_cast<const uint4*>(x + k0);
                float xs[8];
                xs[0] = bf2f(u.x & 0xffffu); xs[1] = bf2f(u.x >> 16);
                xs[2] = bf2f(u.y & 0xffffu); xs[3] = bf2f(u.y >> 16);
                xs[4] = bf2f(u.z & 0xffffu); xs[5] = bf2f(u.z >> 16);
                xs[6] = bf2f(u.w & 0xffffu); xs[7] = bf2f(u.w >> 16);
#pragma unroll
                for (int j = 0; j < 8; j++) {
                    const float* w = Wcol + (size_t)(k0 + j) * 64;
#pragma unroll
                    for (int c = 0; c < 16; c++) acc[c] = fmaf(xs[j], w[c], acc[c]);
                }
            }
        }
    }

    float e1 = 0.f, e2 = 0.f;
#pragma unroll
    for (int c = 0; c < 16; c++) {
        e1 = fmaf(acc[c], alf[cg * 16 + c], e1);
        e2 = fmaf(acc[c], arf[cg * 16 + c], e2);
    }
    if constexpr (H == 4) {
        if (act) {
            el[(size_t)n * 4 + cg] = e1;
            er[(size_t)n * 4 + cg] = e2;
        }
    } else {             // H == 1: reduce partial dots across the 4 waves
        __shared__ float sel_[4][64];
        __shared__ float ser_[4][64];
        sel_[cg][lane] = e1;
        ser_[cg][lane] = e2;
        __syncthreads();
        if (cg == 0 && act) {
            el[n] = sel_[0][lane] + sel_[1][lane] + sel_[2][lane] + sel_[3][lane];
            er[n] = ser_[0][lane] + ser_[1][lane] + ser_[2][lane] + ser_[3][lane];
        }
    }

    if (act) {
        u16* dp = fo + (size_t)n * 64 + cg * 16;
        uint4 v;
        v.x = f2bf_bits(acc[0])  | (f2bf_bits(acc[1])  << 16);
        v.y = f2bf_bits(acc[2])  | (f2bf_bits(acc[3])  << 16);
        v.z = f2bf_bits(acc[4])  | (f2bf_bits(acc[5])  << 16);
        v.w = f2bf_bits(acc[6])  | (f2bf_bits(acc[7])  << 16);
        *reinterpret_cast<uint4*>(dp) = v;
        v.x = f2bf_bits(acc[8])  | (f2bf_bits(acc[9])  << 16);
        v.y = f2bf_bits(acc[10]) | (f2bf_bits(acc[11]) << 16);
        v.z = f2bf_bits(acc[12]) | (f2bf_bits(acc[13]) << 16);
        v.w = f2bf_bits(acc[14]) | (f2bf_bits(acc[15]) << 16);
        *reinterpret_cast<uint4*>(dp + 8) = v;
    }
}

// ---------------- wave-per-node softmax aggregation (R5 loop, widened to 8) ----------------
// One wave per node (R5-proven). Plain consecutive lane-replicated vector loads
// (R6 int4/peel, R7 scalar-pipe, R9 interleave all measured WORSE). 8-wide batch
// puts 16 independent gathers in flight, halving the dependent-chain count vs R5.
// No max-subtraction: |scores| <~ 15 << 88 (fp32 exp overflow) -> sums associative.
template<int H, bool FINAL>
__global__ __launch_bounds__(256) void aggregate(
    const int* __restrict__ flag,
    const u16* __restrict__ fo, const float* __restrict__ el, const float* __restrict__ er,
    const int* __restrict__ row_start, const int* __restrict__ csr_src,
    const float* __restrict__ bias, void* __restrict__ outp, int N)
{
    int gid  = blockIdx.x * 256 + threadIdx.x;
    int n    = gid >> 6;
    int lane = gid & 63;
    if (n >= N) return;
    constexpr int D = 64 / H;
    int h = lane / D;
    float erh = er[(size_t)n * H + h];
    int i0 = row_start[n], i1 = row_start[n + 1];
    float s0 = 0.f, s1 = 0.f, a0 = 0.f, a1 = 0.f;
    int i = i0;
    // 8-wide batches: consecutive plain loads, 16 gathers in flight
    for (; i + 8 <= i1; i += 8) {
        int sA = csr_src[i+0], sB = csr_src[i+1], sC = csr_src[i+2], sD = csr_src[i+3];
        int sE = csr_src[i+4], sF = csr_src[i+5], sG = csr_src[i+6], sH = csr_src[i+7];
        float vA = el[(size_t)sA * H + h] + erh;
        float vB = el[(size_t)sB * H + h] + erh;
        float vC = el[(size_t)sC * H + h] + erh;
        float vD = el[(size_t)sD * H + h] + erh;
        float vE = el[(size_t)sE * H + h] + erh;
        float vF = el[(size_t)sF * H + h] + erh;
        float vG = el[(size_t)sG * H + h] + erh;
        float vH = el[(size_t)sH * H + h] + erh;
        float fA = bf2f(fo[(size_t)sA * 64 + lane]);
        float fB = bf2f(fo[(size_t)sB * 64 + lane]);
        float fC = bf2f(fo[(size_t)sC * 64 + lane]);
        float fD = bf2f(fo[(size_t)sD * 64 + lane]);
        float fE = bf2f(fo[(size_t)sE * 64 + lane]);
        float fF = bf2f(fo[(size_t)sF * 64 + lane]);
        float fG = bf2f(fo[(size_t)sG * 64 + lane]);
        float fH = bf2f(fo[(size_t)sH * 64 + lane]);
        vA = fmaxf(vA, 0.2f * vA); vB = fmaxf(vB, 0.2f * vB);
        vC = fmaxf(vC, 0.2f * vC); vD = fmaxf(vD, 0.2f * vD);
        vE = fmaxf(vE, 0.2f * vE); vF = fmaxf(vF, 0.2f * vF);
        vG = fmaxf(vG, 0.2f * vG); vH = fmaxf(vH, 0.2f * vH);
        float eA = __expf(vA), eB = __expf(vB), eC = __expf(vC), eD = __expf(vD);
        float eE = __expf(vE), eF = __expf(vF), eG = __expf(vG), eH = __expf(vH);
        s0 += (eA + eC) + (eE + eG);
        s1 += (eB + eD) + (eF + eH);
        a0 = fmaf(eA, fA, a0); a1 = fmaf(eB, fB, a1);
        a0 = fmaf(eC, fC, a0); a1 = fmaf(eD, fD, a1);
        a0 = fmaf(eE, fE, a0); a1 = fmaf(eF, fF, a1);
        a0 = fmaf(eG, fG, a0); a1 = fmaf(eH, fH, a1);
    }
    // 4-wide batch (R5's proven body)
    for (; i + 4 <= i1; i += 4) {
        int sA = csr_src[i], sB = csr_src[i + 1], sC = csr_src[i + 2], sD = csr_src[i + 3];
        float vA = el[(size_t)sA * H + h] + erh;
        float vB = el[(size_t)sB * H + h] + erh;
        float vC = el[(size_t)sC * H + h] + erh;
        float vD = el[(size_t)sD * H + h] + erh;
        float fA = bf2f(fo[(size_t)sA * 64 + lane]);
        float fB = bf2f(fo[(size_t)sB * 64 + lane]);
        float fC = bf2f(fo[(size_t)sC * 64 + lane]);
        float fD = bf2f(fo[(size_t)sD * 64 + lane]);
        vA = fmaxf(vA, 0.2f * vA); vB = fmaxf(vB, 0.2f * vB);
        vC = fmaxf(vC, 0.2f * vC); vD = fmaxf(vD, 0.2f * vD);
        float eA = __expf(vA), eB = __expf(vB), eC = __expf(vC), eD = __expf(vD);
        s0 += eA + eC;  s1 += eB + eD;
        a0 = fmaf(eA, fA, a0); a1 = fmaf(eB, fB, a1);
        a0 = fmaf(eC, fC, a0); a1 = fmaf(eD, fD, a1);
    }
    // remainder
    for (; i < i1; i++) {
        int s = csr_src[i];
        float v = el[(size_t)s * H + h] + erh;
        v = fmaxf(v, 0.2f * v);
        float ex = __expf(v);
        float fv = bf2f(fo[(size_t)s * 64 + lane]);
        s0 += ex;
        a0 = fmaf(ex, fv, a0);
    }
    float sumex = s0 + s1;
    float acc   = a0 + a1;
    float o = (i1 > i0) ? (acc / sumex + bias[lane]) : bias[lane];   // 0-in-degree -> bias
    size_t idx = (size_t)n * 64 + lane;
    if constexpr (!FINAL) {
        o = o > 0.f ? o : expm1f(o);                   // ELU
        ((u16*)outp)[idx] = f2bf_bits(o);
    } else {
        if (*flag) ((float*)outp)[idx] = o;
        else       ((u16*)outp)[idx]   = f2bf_bits(o);
    }
}

extern "C" void kernel_launch(void* const* d_in, const int* in_sizes, int n_in,
                              void* d_out, int out_size, void* d_ws, size_t ws_size,
                              hipStream_t stream)
{
    const void* h   = d_in[0];
    const int*  src = (const int*)d_in[1];
    const int*  dst = (const int*)d_in[2];

    const int N  = in_sizes[0] / 128;
    const int E  = in_sizes[1];
    const int NP = (N + 1023) & ~1023;     // padded for int4 scan

    // ---- workspace carve-out (~22 MB) ----
    char* ws = (char*)d_ws;
    size_t off = 0;
    auto take = [&](size_t bytes) -> char* {
        char* p = ws + off;
        off = (off + bytes + 255) & ~(size_t)255;
        return p;
    };
    float* P         = (float*)take(16960 * 4);
    int*   flag      = (int*)  take(256);
    float* el        = (float*)take((size_t)N * 4 * 4);
    float* er        = (float*)take((size_t)N * 4 * 4);
    int*   deg       = (int*)  take((size_t)NP * 4);
    int*   row_start = (int*)  take((size_t)NP * 4);   // covers N+1
    int*   rank      = (int*)  take((size_t)E * 4);
    int*   csr_src   = (int*)  take((size_t)E * 4);
    u16*   f         = (u16*)  take((size_t)N * 64 * 2);   // bf16 activations
    u16*   x1        = (u16*)  take((size_t)N * 64 * 2);
    if (off > ws_size) x1 = (u16*)d_out;   // fallback: x1 in d_out (consumed before final write)

    float* Wf0  = P;          float* Wf1  = P + 8192;  float* Wf2  = P + 12288;
    float* alf0 = P + 16384;  float* arf0 = P + 16448; float* bf0  = P + 16512;
    float* alf1 = P + 16576;  float* arf1 = P + 16640; float* bf1  = P + 16704;
    float* alf2 = P + 16768;  float* arf2 = P + 16832; float* bf2  = P + 16896;

    int setup_blocks = 67 + (NP + 255) / 256;
    setup_kernel<<<setup_blocks, 256, 0, stream>>>((const u32*)h, flag, deg, NP,
        d_in[3], d_in[4], d_in[5], d_in[6],
        d_in[7], d_in[8], d_in[9], d_in[10],
        d_in[11], d_in[12], d_in[13], d_in[14], P);
    hist_rank<<<(E + 255) / 256, 256, 0, stream>>>(dst, deg, rank, E);
    scan_all<<<1, 1024, 0, stream>>>(deg, row_start, NP / 4);
    scatter_kernel<<<(E + 255) / 256, 256, 0, stream>>>(src, dst, rank, row_start, csr_src, E);

    int gemm_blocks = (N + 63) / 64;          // 4 waves/block, 16 cols each
    int agg_blocks  = (N * 64 + 255) / 256;   // one 64-lane wave per node

    // layer 0: 128 -> 4x16
    gemm_attn<128, 4, true ><<<gemm_blocks, 256, 0, stream>>>(flag, h,  Wf0, alf0, arf0, f, el, er, N);
    aggregate<4, false><<<agg_blocks, 256, 0, stream>>>(flag, f, el, er, row_start, csr_src, bf0, x1, N);
    // layer 1: 64 -> 4x16
    gemm_attn<64, 4, false><<<gemm_blocks, 256, 0, stream>>>(flag, x1, Wf1, alf1, arf1, f, el, er, N);
    aggregate<4, false><<<agg_blocks, 256, 0, stream>>>(flag, f, el, er, row_start, csr_src, bf1, x1, N);
    // layer 2: 64 -> 1x64 (final)
    gemm_attn<64, 1, false><<<gemm_blocks, 256, 0, stream>>>(flag, x1, Wf2, alf2, arf2, f, el, er, N);
    aggregate<1, true ><<<agg_blocks, 256, 0, stream>>>(flag, f, el, er, row_start, csr_src, bf2, d_out, N);
}